// Round 1
// baseline (324.220 us; speedup 1.0000x reference)
//
#include <hip/hip_runtime.h>
#include <math.h>

#define KE_C     14.3996f
#define ALPHA_C  0.3f
#define CUTOFF_C 10.0f
#define TWO_PI_C 6.28318530717958647692f

// ---------------- kernel 1: per-molecule reciprocal box + |det| ----------------
__global__ __launch_bounds__(64) void k_cell(const float* __restrict__ cell,
                                             float* __restrict__ RB,
                                             float* __restrict__ VB, int nmol) {
    int m = blockIdx.x * blockDim.x + threadIdx.x;
    if (m >= nmol) return;
    const float* c = cell + m * 9;
    float a00 = c[0], a01 = c[1], a02 = c[2];
    float a10 = c[3], a11 = c[4], a12 = c[5];
    float a20 = c[6], a21 = c[7], a22 = c[8];
    float det = a00 * (a11 * a22 - a12 * a21)
              - a01 * (a10 * a22 - a12 * a20)
              + a02 * (a10 * a21 - a11 * a20);
    float id = 1.0f / det;
    float inv00 = (a11 * a22 - a12 * a21) * id;
    float inv01 = (a02 * a21 - a01 * a22) * id;
    float inv02 = (a01 * a12 - a02 * a11) * id;
    float inv10 = (a12 * a20 - a10 * a22) * id;
    float inv11 = (a00 * a22 - a02 * a20) * id;
    float inv12 = (a02 * a10 - a00 * a12) * id;
    float inv20 = (a10 * a21 - a11 * a20) * id;
    float inv21 = (a01 * a20 - a00 * a21) * id;
    float inv22 = (a00 * a11 - a01 * a10) * id;
    // recip_box[d][e] = 2*pi * inv[e][d]   (transpose of inverse)
    float* rb = RB + m * 9;
    rb[0] = TWO_PI_C * inv00; rb[1] = TWO_PI_C * inv10; rb[2] = TWO_PI_C * inv20;
    rb[3] = TWO_PI_C * inv01; rb[4] = TWO_PI_C * inv11; rb[5] = TWO_PI_C * inv21;
    rb[6] = TWO_PI_C * inv02; rb[7] = TWO_PI_C * inv12; rb[8] = TWO_PI_C * inv22;
    VB[m] = fabsf(det);
}

// ---------------- kernel 2: per-atom s = recip_box[m] . R, q; self-interaction ----------------
__global__ __launch_bounds__(256) void k_atoms(const float* __restrict__ R,
                                               const float* __restrict__ q,
                                               const int* __restrict__ idx_m,
                                               const float* __restrict__ RB,
                                               float4* __restrict__ S4,
                                               float* __restrict__ SI, int natoms) {
    __shared__ float si[64];
    int tid = threadIdx.x;
    if (tid < 64) si[tid] = 0.0f;
    __syncthreads();
    int a = blockIdx.x * 256 + tid;
    if (a < natoms) {
        int m = idx_m[a];
        float r0 = R[3 * a], r1 = R[3 * a + 1], r2 = R[3 * a + 2];
        const float* rb = RB + m * 9;
        float s0 = rb[0] * r0 + rb[1] * r1 + rb[2] * r2;
        float s1 = rb[3] * r0 + rb[4] * r1 + rb[5] * r2;
        float s2 = rb[6] * r0 + rb[7] * r1 + rb[8] * r2;
        float qa = q[a];
        S4[a] = make_float4(s0, s1, s2, qa);
        atomicAdd(&si[m & 63], qa * qa);
    }
    __syncthreads();
    if (tid < 64) atomicAdd(&SI[tid], si[tid]);
}

// ---------------- kernel 3: real-space pair sum ----------------
__global__ __launch_bounds__(256) void k_real(const float* __restrict__ Rij,
                                              const int* __restrict__ idx_i,
                                              const int* __restrict__ idx_j,
                                              const int* __restrict__ idx_m,
                                              const float* __restrict__ q,
                                              float* __restrict__ YR, int npairs) {
    __shared__ float acc[64];
    int tid = threadIdx.x;
    if (tid < 64) acc[tid] = 0.0f;
    __syncthreads();
    const float sqa = 0.5477225575051661f;               // sqrt(0.3)
    const float frcut = erfcf(sqa * CUTOFF_C) / CUTOFF_C;
    int stride = gridDim.x * blockDim.x;
    for (int p = blockIdx.x * blockDim.x + tid; p < npairs; p += stride) {
        float x = Rij[3 * p], y = Rij[3 * p + 1], z = Rij[3 * p + 2];
        float d = sqrtf(x * x + y * y + z * z);
        if (d <= CUTOFF_C) {
            int i = idx_i[p], j = idx_j[p];
            float pot = q[i] * q[j] * (erfcf(sqa * d) / d - frcut);
            atomicAdd(&acc[idx_m[i] & 63], pot);
        }
    }
    __syncthreads();
    if (tid < 64) atomicAdd(&YR[tid], acc[tid]);
}

// ---------------- kernel 4: structure factors S(m,k) = sum_a q cos/sin(k.s) ----------------
// Block handles 128 consecutive atoms (sorted by molecule); 256 threads each own
// ceil(nk/256)=4 k-vectors, accumulate in registers, flush at molecule boundaries.
__global__ __launch_bounds__(256) void k_recip(const float4* __restrict__ S4,
                                               const int* __restrict__ idx_m,
                                               const float* __restrict__ kvecs,
                                               float* __restrict__ QR,
                                               float* __restrict__ QI,
                                               int natoms, int nk) {
    __shared__ float4 sA[128];
    __shared__ int sM[128];
    int tid = threadIdx.x;
    int base = blockIdx.x * 128;
    if (tid < 128) {
        int a = base + tid;
        if (a < natoms) { sA[tid] = S4[a]; sM[tid] = idx_m[a]; }
        else sM[tid] = -1;
    }
    __syncthreads();
    float kx[4], ky[4], kz[4];
#pragma unroll
    for (int j = 0; j < 4; ++j) {
        int k = tid + j * 256;
        if (k < nk) { kx[j] = kvecs[3 * k]; ky[j] = kvecs[3 * k + 1]; kz[j] = kvecs[3 * k + 2]; }
        else { kx[j] = 0.0f; ky[j] = 0.0f; kz[j] = 0.0f; }
    }
    float qr[4] = {0.f, 0.f, 0.f, 0.f};
    float qi[4] = {0.f, 0.f, 0.f, 0.f};
    int cur = sM[0];
    for (int t = 0; t < 128; ++t) {
        int m = sM[t];
        if (m < 0) break;                 // past end of atom array (uniform)
        if (m != cur) {                   // molecule boundary (uniform, rare)
#pragma unroll
            for (int j = 0; j < 4; ++j) {
                int k = tid + j * 256;
                if (k < nk) {
                    atomicAdd(&QR[cur * nk + k], qr[j]);
                    atomicAdd(&QI[cur * nk + k], qi[j]);
                }
                qr[j] = 0.0f; qi[j] = 0.0f;
            }
            cur = m;
        }
        float4 s = sA[t];
#pragma unroll
        for (int j = 0; j < 4; ++j) {
            float ph = kx[j] * s.x + ky[j] * s.y + kz[j] * s.z;
            float sn, cs;
            __sincosf(ph, &sn, &cs);
            qr[j] += s.w * cs;
            qi[j] += s.w * sn;
        }
    }
    if (cur >= 0) {
#pragma unroll
        for (int j = 0; j < 4; ++j) {
            int k = tid + j * 256;
            if (k < nk) {
                atomicAdd(&QR[cur * nk + k], qr[j]);
                atomicAdd(&QI[cur * nk + k], qi[j]);
            }
        }
    }
}

// ---------------- kernel 5: finalize per molecule ----------------
__global__ __launch_bounds__(256) void k_final(const float* __restrict__ kvecs,
                                               const float* __restrict__ RB,
                                               const float* __restrict__ VB,
                                               const float* __restrict__ QR,
                                               const float* __restrict__ QI,
                                               const float* __restrict__ YR,
                                               const float* __restrict__ SI,
                                               float* __restrict__ out, int nk) {
    int m = blockIdx.x;
    int tid = threadIdx.x;
    __shared__ float rb[9];
    __shared__ float wsum[4];
    if (tid < 9) rb[tid] = RB[m * 9 + tid];
    __syncthreads();
    float acc = 0.0f;
    for (int k = tid; k < nk; k += 256) {
        float gx = kvecs[3 * k], gy = kvecs[3 * k + 1], gz = kvecs[3 * k + 2];
        float kv0 = gx * rb[0] + gy * rb[3] + gz * rb[6];
        float kv1 = gx * rb[1] + gy * rb[4] + gz * rb[7];
        float kv2 = gx * rb[2] + gy * rb[5] + gz * rb[8];
        float ksq = kv0 * kv0 + kv1 * kv1 + kv2 * kv2;
        float qr = QR[m * nk + k], qi = QI[m * nk + k];
        acc += (qr * qr + qi * qi) * __expf(-0.25f / ALPHA_C * ksq) / ksq;
    }
#pragma unroll
    for (int off = 32; off > 0; off >>= 1) acc += __shfl_down(acc, off, 64);
    if ((tid & 63) == 0) wsum[tid >> 6] = acc;
    __syncthreads();
    if (tid == 0) {
        float s = wsum[0] + wsum[1] + wsum[2] + wsum[3];
        float pref = TWO_PI_C / VB[m];
        float self_c = sqrtf(ALPHA_C / 3.14159265358979323846f);
        out[m] = 0.5f * KE_C * YR[m] + KE_C * (pref * s - self_c * SI[m]);
    }
}

extern "C" void kernel_launch(void* const* d_in, const int* in_sizes, int n_in,
                              void* d_out, int out_size, void* d_ws, size_t ws_size,
                              hipStream_t stream) {
    const float* q     = (const float*)d_in[0];   // [A,1]
    const float* Rij   = (const float*)d_in[1];   // [P,3]
    const float* R     = (const float*)d_in[2];   // [A,3]
    const float* cell  = (const float*)d_in[3];   // [M,3,3]
    const float* kvecs = (const float*)d_in[4];   // [K,3]
    const int*   idx_m = (const int*)d_in[5];     // [A]
    const int*   idx_i = (const int*)d_in[6];     // [P]
    const int*   idx_j = (const int*)d_in[7];     // [P]

    int natoms = in_sizes[0];
    int npairs = in_sizes[1] / 3;
    int nmol   = in_sizes[3] / 9;
    int nk     = in_sizes[4] / 3;
    float* out = (float*)d_out;

    // workspace layout (floats)
    float*  W  = (float*)d_ws;
    float*  RB = W;                                // nmol*9
    float*  VB = RB + (size_t)nmol * 9;            // nmol
    float4* S4 = (float4*)(VB + nmol);             // natoms float4 (offset 640 floats for nmol=64 -> 16B aligned)
    float*  QR = (float*)(S4 + natoms);            // nmol*nk
    float*  QI = QR + (size_t)nmol * nk;           // nmol*nk
    float*  YR = QI + (size_t)nmol * nk;           // nmol
    float*  SI = YR + nmol;                        // nmol
    size_t total_bytes = (size_t)((char*)(SI + nmol) - (char*)W);

    hipMemsetAsync(d_ws, 0, total_bytes, stream);

    k_cell<<<(nmol + 63) / 64, 64, 0, stream>>>(cell, RB, VB, nmol);
    k_atoms<<<(natoms + 255) / 256, 256, 0, stream>>>(R, q, idx_m, RB, S4, SI, natoms);
    k_real<<<1024, 256, 0, stream>>>(Rij, idx_i, idx_j, idx_m, q, YR, npairs);
    k_recip<<<(natoms + 127) / 128, 256, 0, stream>>>(S4, idx_m, kvecs, QR, QI, natoms, nk);
    k_final<<<nmol, 256, 0, stream>>>(kvecs, RB, VB, QR, QI, YR, SI, out, nk);
}

// Round 2
// 272.638 us; speedup vs baseline: 1.1892x; 1.1892x over previous
//
#include <hip/hip_runtime.h>
#include <math.h>

#define KE_C     14.3996f
#define ALPHA_C  0.3f
#define CUTOFF_C 10.0f
#define TWO_PI_C 6.283185307179586f
#define RBLOCKS  2048
#define KSPL     4
#define ASPL     4

// ---------------- kernel 1: per-molecule reciprocal box + |det| ----------------
__global__ __launch_bounds__(64) void k_cell(const float* __restrict__ cell,
                                             float* __restrict__ RB,
                                             float* __restrict__ VB, int nmol) {
    int m = blockIdx.x * blockDim.x + threadIdx.x;
    if (m >= nmol) return;
    const float* c = cell + m * 9;
    float a00 = c[0], a01 = c[1], a02 = c[2];
    float a10 = c[3], a11 = c[4], a12 = c[5];
    float a20 = c[6], a21 = c[7], a22 = c[8];
    float det = a00 * (a11 * a22 - a12 * a21)
              - a01 * (a10 * a22 - a12 * a20)
              + a02 * (a10 * a21 - a11 * a20);
    float id = 1.0f / det;
    float inv00 = (a11 * a22 - a12 * a21) * id;
    float inv01 = (a02 * a21 - a01 * a22) * id;
    float inv02 = (a01 * a12 - a02 * a11) * id;
    float inv10 = (a12 * a20 - a10 * a22) * id;
    float inv11 = (a00 * a22 - a02 * a20) * id;
    float inv12 = (a02 * a10 - a00 * a12) * id;
    float inv20 = (a10 * a21 - a11 * a20) * id;
    float inv21 = (a01 * a20 - a00 * a21) * id;
    float inv22 = (a00 * a11 - a01 * a10) * id;
    // recip_box[d][e] = 2*pi * inv[e][d]   (transpose of inverse), row-major [d][e]
    float* rb = RB + m * 9;
    rb[0] = TWO_PI_C * inv00; rb[1] = TWO_PI_C * inv10; rb[2] = TWO_PI_C * inv20;
    rb[3] = TWO_PI_C * inv01; rb[4] = TWO_PI_C * inv11; rb[5] = TWO_PI_C * inv21;
    rb[6] = TWO_PI_C * inv02; rb[7] = TWO_PI_C * inv12; rb[8] = TWO_PI_C * inv22;
    VB[m] = fabsf(det);
}

// ---------------- kernel 1b: molecule segment bounds (idx_m is sorted) ----------------
__global__ __launch_bounds__(128) void k_bounds(const int* __restrict__ idx_m,
                                                int* __restrict__ bounds,
                                                int natoms, int nmol) {
    int m = threadIdx.x;
    if (m > nmol) return;
    int lo = 0, hi = natoms;
    while (lo < hi) {
        int mid = (lo + hi) >> 1;
        if (idx_m[mid] < m) lo = mid + 1; else hi = mid;
    }
    bounds[m] = lo;
}

// ---------------- kernel 2: per-atom s = recip_box[m] . R; pack (q, mol); self-int ----------------
__global__ __launch_bounds__(256) void k_atoms(const float* __restrict__ R,
                                               const float* __restrict__ q,
                                               const int* __restrict__ idx_m,
                                               const float* __restrict__ RB,
                                               float4* __restrict__ S4,
                                               float2* __restrict__ QM,
                                               float* __restrict__ SI, int natoms) {
    __shared__ float si[64];
    int tid = threadIdx.x;
    if (tid < 64) si[tid] = 0.0f;
    __syncthreads();
    int a = blockIdx.x * 256 + tid;
    if (a < natoms) {
        int m = idx_m[a];
        float r0 = R[3 * a], r1 = R[3 * a + 1], r2 = R[3 * a + 2];
        const float* rb = RB + m * 9;
        float s0 = rb[0] * r0 + rb[1] * r1 + rb[2] * r2;
        float s1 = rb[3] * r0 + rb[4] * r1 + rb[5] * r2;
        float s2 = rb[6] * r0 + rb[7] * r1 + rb[8] * r2;
        float qa = q[a];
        S4[a] = make_float4(s0, s1, s2, qa);
        QM[a] = make_float2(qa, __int_as_float(m));
        atomicAdd(&si[m & 63], qa * qa);
    }
    __syncthreads();
    if (tid < 64) atomicAdd(&SI[tid], si[tid]);
}

// ---------------- kernel 3: real-space pair sum, 4 pairs/thread/iter ----------------
__global__ __launch_bounds__(256) void k_real(const float* __restrict__ Rij,
                                              const int* __restrict__ idx_i,
                                              const int* __restrict__ idx_j,
                                              const float2* __restrict__ QM,
                                              float* __restrict__ YRpad, int npairs) {
    __shared__ float acc[4][64];            // per-wave private accumulators
    int tid = threadIdx.x;
    int wave = tid >> 6;
    if (tid < 256) { acc[tid >> 6][tid & 63] = 0.0f; }
    __syncthreads();
    const float sqa = 0.5477225575051661f;  // sqrt(0.3)
    const float frcut = erfcf(sqa * CUTOFF_C) / CUTOFF_C;
    int nchunk = npairs >> 2;
    int stride = gridDim.x * 256;
    for (int c = blockIdx.x * 256 + tid; c < nchunk; c += stride) {
        int p = c << 2;
        // batched loads: 2x int4 + 3x float4, all independent
        int4 ii = *(const int4*)(idx_i + p);
        int4 jj = *(const int4*)(idx_j + p);
        const float4* r4 = (const float4*)(Rij + 3 * p);
        float4 ra = r4[0], rb = r4[1], rc = r4[2];
        float x0 = ra.x, y0 = ra.y, z0 = ra.z;
        float x1 = ra.w, y1 = rb.x, z1 = rb.y;
        float x2 = rb.z, y2 = rb.w, z2 = rc.x;
        float x3 = rc.y, y3 = rc.z, z3 = rc.w;
        // batched gathers (8 independent float2 loads)
        float2 qi0 = QM[ii.x], qi1 = QM[ii.y], qi2 = QM[ii.z], qi3 = QM[ii.w];
        float2 qj0 = QM[jj.x], qj1 = QM[jj.y], qj2 = QM[jj.z], qj3 = QM[jj.w];
        float d0 = sqrtf(x0 * x0 + y0 * y0 + z0 * z0);
        float d1 = sqrtf(x1 * x1 + y1 * y1 + z1 * z1);
        float d2 = sqrtf(x2 * x2 + y2 * y2 + z2 * z2);
        float d3 = sqrtf(x3 * x3 + y3 * y3 + z3 * z3);
        if (d0 <= CUTOFF_C)
            atomicAdd(&acc[wave][__float_as_int(qi0.y) & 63],
                      qi0.x * qj0.x * (erfcf(sqa * d0) / d0 - frcut));
        if (d1 <= CUTOFF_C)
            atomicAdd(&acc[wave][__float_as_int(qi1.y) & 63],
                      qi1.x * qj1.x * (erfcf(sqa * d1) / d1 - frcut));
        if (d2 <= CUTOFF_C)
            atomicAdd(&acc[wave][__float_as_int(qi2.y) & 63],
                      qi2.x * qj2.x * (erfcf(sqa * d2) / d2 - frcut));
        if (d3 <= CUTOFF_C)
            atomicAdd(&acc[wave][__float_as_int(qi3.y) & 63],
                      qi3.x * qj3.x * (erfcf(sqa * d3) / d3 - frcut));
    }
    // tail (npairs not multiple of 4)
    if (blockIdx.x == 0 && tid == 0) {
        for (int p = nchunk << 2; p < npairs; ++p) {
            float x = Rij[3 * p], y = Rij[3 * p + 1], z = Rij[3 * p + 2];
            float d = sqrtf(x * x + y * y + z * z);
            if (d <= CUTOFF_C) {
                float2 qi = QM[idx_i[p]];
                float2 qj = QM[idx_j[p]];
                atomicAdd(&acc[0][__float_as_int(qi.y) & 63],
                          qi.x * qj.x * (erfcf(sqa * d) / d - frcut));
            }
        }
    }
    __syncthreads();
    if (tid < 64) {
        float v = acc[0][tid] + acc[1][tid] + acc[2][tid] + acc[3][tid];
        atomicAdd(&YRpad[tid * 16], v);     // 64 distinct cache lines
    }
}

// ---------------- kernel 4: structure factors, molecule-centric ----------------
// grid = nmol * KSPL * ASPL blocks; each thread owns one k-vector for one molecule,
// accumulates over an atom sub-range staged through LDS; exactly 2 atomics/thread.
__global__ __launch_bounds__(256) void k_recip(const float4* __restrict__ S4,
                                               const float* __restrict__ kvecs,
                                               const int* __restrict__ bounds,
                                               float* __restrict__ QR,
                                               float* __restrict__ QI, int nk) {
    __shared__ float4 tile[256];
    int tid = threadIdx.x;
    int b = blockIdx.x;
    int m  = b / (KSPL * ASPL);
    int rem = b % (KSPL * ASPL);
    int kc = rem / ASPL;
    int ac = rem % ASPL;
    int s0 = bounds[m], s1 = bounds[m + 1];
    int na = s1 - s0;
    int per = (na + ASPL - 1) / ASPL;
    int a0 = s0 + ac * per;
    int a1 = min(a0 + per, s1);
    int k = kc * 256 + tid;
    float kx = 0.f, ky = 0.f, kz = 0.f;
    if (k < nk) { kx = kvecs[3 * k]; ky = kvecs[3 * k + 1]; kz = kvecs[3 * k + 2]; }
    float qr = 0.f, qi = 0.f;
    for (int t0 = a0; t0 < a1; t0 += 256) {
        __syncthreads();
        int a = t0 + tid;
        if (a < a1) tile[tid] = S4[a];
        __syncthreads();
        int n = min(256, a1 - t0);
#pragma unroll 4
        for (int t = 0; t < n; ++t) {
            float4 s = tile[t];                      // broadcast read
            float ph = kx * s.x + ky * s.y + kz * s.z;
            float sn, cs;
            __sincosf(ph, &sn, &cs);
            qr += s.w * cs;
            qi += s.w * sn;
        }
    }
    if (k < nk) {
        atomicAdd(&QR[m * nk + k], qr);
        atomicAdd(&QI[m * nk + k], qi);
    }
}

// ---------------- kernel 5: finalize per molecule ----------------
__global__ __launch_bounds__(256) void k_final(const float* __restrict__ kvecs,
                                               const float* __restrict__ RB,
                                               const float* __restrict__ VB,
                                               const float* __restrict__ QR,
                                               const float* __restrict__ QI,
                                               const float* __restrict__ YRpad,
                                               const float* __restrict__ SI,
                                               float* __restrict__ out, int nk) {
    int m = blockIdx.x;
    int tid = threadIdx.x;
    __shared__ float rb[9];
    __shared__ float wsum[4];
    if (tid < 9) rb[tid] = RB[m * 9 + tid];
    __syncthreads();
    float acc = 0.0f;
    for (int k = tid; k < nk; k += 256) {
        float gx = kvecs[3 * k], gy = kvecs[3 * k + 1], gz = kvecs[3 * k + 2];
        float kv0 = gx * rb[0] + gy * rb[3] + gz * rb[6];
        float kv1 = gx * rb[1] + gy * rb[4] + gz * rb[7];
        float kv2 = gx * rb[2] + gy * rb[5] + gz * rb[8];
        float ksq = kv0 * kv0 + kv1 * kv1 + kv2 * kv2;
        float qr = QR[m * nk + k], qi = QI[m * nk + k];
        acc += (qr * qr + qi * qi) * __expf(-0.25f / ALPHA_C * ksq) / ksq;
    }
#pragma unroll
    for (int off = 32; off > 0; off >>= 1) acc += __shfl_down(acc, off, 64);
    if ((tid & 63) == 0) wsum[tid >> 6] = acc;
    __syncthreads();
    if (tid == 0) {
        float s = wsum[0] + wsum[1] + wsum[2] + wsum[3];
        float pref = TWO_PI_C / VB[m];
        float self_c = sqrtf(ALPHA_C / 3.14159265358979323846f);
        out[m] = 0.5f * KE_C * YRpad[m * 16] + KE_C * (pref * s - self_c * SI[m]);
    }
}

extern "C" void kernel_launch(void* const* d_in, const int* in_sizes, int n_in,
                              void* d_out, int out_size, void* d_ws, size_t ws_size,
                              hipStream_t stream) {
    const float* q     = (const float*)d_in[0];   // [A,1]
    const float* Rij   = (const float*)d_in[1];   // [P,3]
    const float* R     = (const float*)d_in[2];   // [A,3]
    const float* cell  = (const float*)d_in[3];   // [M,3,3]
    const float* kvecs = (const float*)d_in[4];   // [K,3]
    const int*   idx_m = (const int*)d_in[5];     // [A]
    const int*   idx_i = (const int*)d_in[6];     // [P]
    const int*   idx_j = (const int*)d_in[7];     // [P]

    int natoms = in_sizes[0];
    int npairs = in_sizes[1] / 3;
    int nmol   = in_sizes[3] / 9;
    int nk     = in_sizes[4] / 3;
    float* out = (float*)d_out;

    // workspace layout (float offsets; keeps S4 16B- and QM 8B-aligned)
    float* W      = (float*)d_ws;
    float* RB     = W;                                  // 576
    float* VB     = RB + 576;                           // 64
    int*   bounds = (int*)(VB + 64);                    // 80 ints (padding)
    float4* S4    = (float4*)(W + 720);                 // natoms float4
    float2* QM    = (float2*)(W + 720 + 4 * (size_t)natoms);       // natoms float2
    float* QR     = W + 720 + 6 * (size_t)natoms;       // nmol*nk
    float* QI     = QR + (size_t)nmol * nk;             // nmol*nk
    float* SI     = QI + (size_t)nmol * nk;             // 64
    float* YRpad  = SI + 64;                            // 64*16

    // zero only the atomically-accumulated region (QR, QI, SI, YRpad)
    size_t zero_bytes = ((size_t)2 * nmol * nk + 64 + 64 * 16) * sizeof(float);
    hipMemsetAsync(QR, 0, zero_bytes, stream);

    k_cell  <<<1, 64, 0, stream>>>(cell, RB, VB, nmol);
    k_bounds<<<1, 128, 0, stream>>>(idx_m, bounds, natoms, nmol);
    k_atoms <<<(natoms + 255) / 256, 256, 0, stream>>>(R, q, idx_m, RB, S4, QM, SI, natoms);
    k_real  <<<RBLOCKS, 256, 0, stream>>>(Rij, idx_i, idx_j, QM, YRpad, npairs);
    k_recip <<<nmol * KSPL * ASPL, 256, 0, stream>>>(S4, kvecs, bounds, QR, QI, nk);
    k_final <<<nmol, 256, 0, stream>>>(kvecs, RB, VB, QR, QI, YRpad, SI, out, nk);
}

// Round 4
// 264.720 us; speedup vs baseline: 1.2248x; 1.0299x over previous
//
#include <hip/hip_runtime.h>
#include <math.h>

#define KE_C     14.3996f
#define ALPHA_C  0.3f
#define CUTOFF_C 10.0f
#define TWO_PI_C 6.283185307179586f
#define KSPL     4
#define ASPL     4
#define NRECIP   1024          // nmol(64) * KSPL * ASPL — must match launch

typedef float vfloat4 __attribute__((ext_vector_type(4)));
typedef int   vint4   __attribute__((ext_vector_type(4)));

// fast erfc: Abramowitz & Stegun 7.1.26, |abs err| < 1.5e-7
__device__ __forceinline__ float fast_erfc(float x) {
    float t = __builtin_amdgcn_rcpf(fmaf(0.3275911f, x, 1.0f));
    float p = fmaf(t, 1.061405429f, -1.453152027f);
    p = fmaf(t, p, 1.421413741f);
    p = fmaf(t, p, -0.284496736f);
    p = fmaf(t, p, 0.254829592f);
    return t * p * __expf(-x * x);
}

// ---------------- kernel 1: per-molecule reciprocal box + |det| ----------------
__global__ __launch_bounds__(64) void k_cell(const float* __restrict__ cell,
                                             float* __restrict__ RB,
                                             float* __restrict__ VB, int nmol) {
    int m = blockIdx.x * blockDim.x + threadIdx.x;
    if (m >= nmol) return;
    const float* c = cell + m * 9;
    float a00 = c[0], a01 = c[1], a02 = c[2];
    float a10 = c[3], a11 = c[4], a12 = c[5];
    float a20 = c[6], a21 = c[7], a22 = c[8];
    float det = a00 * (a11 * a22 - a12 * a21)
              - a01 * (a10 * a22 - a12 * a20)
              + a02 * (a10 * a21 - a11 * a20);
    float id = 1.0f / det;
    float inv00 = (a11 * a22 - a12 * a21) * id;
    float inv01 = (a02 * a21 - a01 * a22) * id;
    float inv02 = (a01 * a12 - a02 * a11) * id;
    float inv10 = (a12 * a20 - a10 * a22) * id;
    float inv11 = (a00 * a22 - a02 * a20) * id;
    float inv12 = (a02 * a10 - a00 * a12) * id;
    float inv20 = (a10 * a21 - a11 * a20) * id;
    float inv21 = (a01 * a20 - a00 * a21) * id;
    float inv22 = (a00 * a11 - a01 * a10) * id;
    float* rb = RB + m * 9;   // recip_box[d][e] = 2*pi * inv[e][d]
    rb[0] = TWO_PI_C * inv00; rb[1] = TWO_PI_C * inv10; rb[2] = TWO_PI_C * inv20;
    rb[3] = TWO_PI_C * inv01; rb[4] = TWO_PI_C * inv11; rb[5] = TWO_PI_C * inv21;
    rb[6] = TWO_PI_C * inv02; rb[7] = TWO_PI_C * inv12; rb[8] = TWO_PI_C * inv22;
    VB[m] = fabsf(det);
}

// ---------------- kernel 1b: molecule segment bounds (idx_m is sorted) ----------------
__global__ __launch_bounds__(128) void k_bounds(const int* __restrict__ idx_m,
                                                int* __restrict__ bounds,
                                                int natoms, int nmol) {
    int m = threadIdx.x;
    if (m > nmol) return;
    int lo = 0, hi = natoms;
    while (lo < hi) {
        int mid = (lo + hi) >> 1;
        if (idx_m[mid] < m) lo = mid + 1; else hi = mid;
    }
    bounds[m] = lo;
}

// ---------------- kernel 2: per-atom s = recip_box[m].R; pack (q,mol); self-int ----------------
__global__ __launch_bounds__(256) void k_atoms(const float* __restrict__ R,
                                               const float* __restrict__ q,
                                               const int* __restrict__ idx_m,
                                               const float* __restrict__ RB,
                                               float4* __restrict__ S4,
                                               float2* __restrict__ QM,
                                               float* __restrict__ SI, int natoms) {
    __shared__ float si[64];
    int tid = threadIdx.x;
    if (tid < 64) si[tid] = 0.0f;
    __syncthreads();
    int a = blockIdx.x * 256 + tid;
    if (a < natoms) {
        int m = idx_m[a];
        float r0 = R[3 * a], r1 = R[3 * a + 1], r2 = R[3 * a + 2];
        const float* rb = RB + m * 9;
        float s0 = rb[0] * r0 + rb[1] * r1 + rb[2] * r2;
        float s1 = rb[3] * r0 + rb[4] * r1 + rb[5] * r2;
        float s2 = rb[6] * r0 + rb[7] * r1 + rb[8] * r2;
        float qa = q[a];
        S4[a] = make_float4(s0, s1, s2, qa);
        QM[a] = make_float2(qa, __int_as_float(m));
        atomicAdd(&si[m & 63], qa * qa);
    }
    __syncthreads();
    if (tid < 64) atomicAdd(&SI[tid], si[tid]);
}

// ---------------- fused main kernel: recip blocks [0,NRECIP), real blocks after ----------------
__global__ __launch_bounds__(256) void k_main(const float4* __restrict__ S4,
                                              const float* __restrict__ kvecs,
                                              const int* __restrict__ bounds,
                                              float* __restrict__ QR,
                                              float* __restrict__ QI, int nk,
                                              const float* __restrict__ Rij,
                                              const int* __restrict__ idx_i,
                                              const int* __restrict__ idx_j,
                                              const float2* __restrict__ QM,
                                              float* __restrict__ YRpad, int npairs) {
    __shared__ float acc[4][64];
    int tid = threadIdx.x;
    int bid = blockIdx.x;

    if (bid < NRECIP) {
        // ---- reciprocal: one k-vector per thread, wave-uniform atom loads ----
        int m  = bid >> 4;
        int kc = (bid >> 2) & 3;
        int ac = bid & 3;
        int s0 = bounds[m], s1 = bounds[m + 1];
        int per = (s1 - s0 + ASPL - 1) / ASPL;
        int a0 = s0 + ac * per;
        int a1 = min(a0 + per, s1);
        int k = kc * 256 + tid;
        float kx = 0.f, ky = 0.f, kz = 0.f;
        if (k < nk) { kx = kvecs[3 * k]; ky = kvecs[3 * k + 1]; kz = kvecs[3 * k + 2]; }
        float qr = 0.f, qi = 0.f;
#pragma unroll 4
        for (int t = a0; t < a1; ++t) {
            float4 s = S4[t];                 // uniform address -> scalar/broadcast load
            float ph = fmaf(kx, s.x, fmaf(ky, s.y, kz * s.z));
            float sn, cs;
            __sincosf(ph, &sn, &cs);
            qr = fmaf(s.w, cs, qr);
            qi = fmaf(s.w, sn, qi);
        }
        if (k < nk) {
            atomicAdd(&QR[m * nk + k], qr);
            atomicAdd(&QI[m * nk + k], qi);
        }
    } else {
        // ---- real space: 8 pairs per thread, one chunk per thread ----
        int wave = tid >> 6;
        ((float*)acc)[tid] = 0.0f;
        __syncthreads();
        const float sqa = 0.5477225575051661f;      // sqrt(0.3)
        const float frcut = fast_erfc(sqa * CUTOFF_C) / CUTOFF_C;
        long base = ((long)(bid - NRECIP) * 256 + tid) << 3;
        if (base + 8 <= npairs) {
            vint4 ii0 = __builtin_nontemporal_load((const vint4*)(idx_i + base));
            vint4 ii1 = __builtin_nontemporal_load((const vint4*)(idx_i + base) + 1);
            vint4 jj0 = __builtin_nontemporal_load((const vint4*)(idx_j + base));
            vint4 jj1 = __builtin_nontemporal_load((const vint4*)(idx_j + base) + 1);
            const vfloat4* r4 = (const vfloat4*)(Rij + 3 * base);
            vfloat4 A = __builtin_nontemporal_load(r4 + 0);
            vfloat4 B = __builtin_nontemporal_load(r4 + 1);
            vfloat4 C = __builtin_nontemporal_load(r4 + 2);
            vfloat4 D = __builtin_nontemporal_load(r4 + 3);
            vfloat4 E = __builtin_nontemporal_load(r4 + 4);
            vfloat4 F = __builtin_nontemporal_load(r4 + 5);
            float2 qa0 = QM[ii0.x], qa1 = QM[ii0.y], qa2 = QM[ii0.z], qa3 = QM[ii0.w];
            float2 qa4 = QM[ii1.x], qa5 = QM[ii1.y], qa6 = QM[ii1.z], qa7 = QM[ii1.w];
            float2 qb0 = QM[jj0.x], qb1 = QM[jj0.y], qb2 = QM[jj0.z], qb3 = QM[jj0.w];
            float2 qb4 = QM[jj1.x], qb5 = QM[jj1.y], qb6 = QM[jj1.z], qb7 = QM[jj1.w];
#define PAIR(xx, yy, zz, qa, qb)                                              \
            {                                                                 \
                float d2 = fmaf(xx, xx, fmaf(yy, yy, (zz) * (zz)));           \
                if (d2 <= CUTOFF_C * CUTOFF_C) {                              \
                    float rd = __builtin_amdgcn_rsqf(d2);                     \
                    float d = d2 * rd;                                        \
                    float f = fast_erfc(sqa * d) * rd - frcut;                \
                    atomicAdd(&acc[wave][__float_as_int((qa).y) & 63],        \
                              (qa).x * (qb).x * f);                           \
                }                                                             \
            }
            PAIR(A.x, A.y, A.z, qa0, qb0)
            PAIR(A.w, B.x, B.y, qa1, qb1)
            PAIR(B.z, B.w, C.x, qa2, qb2)
            PAIR(C.y, C.z, C.w, qa3, qb3)
            PAIR(D.x, D.y, D.z, qa4, qb4)
            PAIR(D.w, E.x, E.y, qa5, qb5)
            PAIR(E.z, E.w, F.x, qa6, qb6)
            PAIR(F.y, F.z, F.w, qa7, qb7)
#undef PAIR
        } else if (base < npairs) {
            for (long p = base; p < npairs; ++p) {
                float x = Rij[3 * p], y = Rij[3 * p + 1], z = Rij[3 * p + 2];
                float d2 = fmaf(x, x, fmaf(y, y, z * z));
                if (d2 <= CUTOFF_C * CUTOFF_C) {
                    float rd = __builtin_amdgcn_rsqf(d2);
                    float d = d2 * rd;
                    float2 qi2 = QM[idx_i[p]];
                    float2 qj2 = QM[idx_j[p]];
                    atomicAdd(&acc[wave][__float_as_int(qi2.y) & 63],
                              qi2.x * qj2.x * (fast_erfc(sqa * d) * rd - frcut));
                }
            }
        }
        __syncthreads();
        if (tid < 64) {
            float v = acc[0][tid] + acc[1][tid] + acc[2][tid] + acc[3][tid];
            atomicAdd(&YRpad[tid * 16], v);
        }
    }
}

// ---------------- finalize per molecule ----------------
__global__ __launch_bounds__(256) void k_final(const float* __restrict__ kvecs,
                                               const float* __restrict__ RB,
                                               const float* __restrict__ VB,
                                               const float* __restrict__ QR,
                                               const float* __restrict__ QI,
                                               const float* __restrict__ YRpad,
                                               const float* __restrict__ SI,
                                               float* __restrict__ out, int nk) {
    int m = blockIdx.x;
    int tid = threadIdx.x;
    __shared__ float rb[9];
    __shared__ float wsum[4];
    if (tid < 9) rb[tid] = RB[m * 9 + tid];
    __syncthreads();
    float acc = 0.0f;
    for (int k = tid; k < nk; k += 256) {
        float gx = kvecs[3 * k], gy = kvecs[3 * k + 1], gz = kvecs[3 * k + 2];
        float kv0 = gx * rb[0] + gy * rb[3] + gz * rb[6];
        float kv1 = gx * rb[1] + gy * rb[4] + gz * rb[7];
        float kv2 = gx * rb[2] + gy * rb[5] + gz * rb[8];
        float ksq = kv0 * kv0 + kv1 * kv1 + kv2 * kv2;
        float qr = QR[m * nk + k], qi = QI[m * nk + k];
        acc += (qr * qr + qi * qi) * __expf(-0.25f / ALPHA_C * ksq) / ksq;
    }
#pragma unroll
    for (int off = 32; off > 0; off >>= 1) acc += __shfl_down(acc, off, 64);
    if ((tid & 63) == 0) wsum[tid >> 6] = acc;
    __syncthreads();
    if (tid == 0) {
        float s = wsum[0] + wsum[1] + wsum[2] + wsum[3];
        float pref = TWO_PI_C / VB[m];
        float self_c = sqrtf(ALPHA_C / 3.14159265358979323846f);
        out[m] = 0.5f * KE_C * YRpad[m * 16] + KE_C * (pref * s - self_c * SI[m]);
    }
}

extern "C" void kernel_launch(void* const* d_in, const int* in_sizes, int n_in,
                              void* d_out, int out_size, void* d_ws, size_t ws_size,
                              hipStream_t stream) {
    const float* q     = (const float*)d_in[0];   // [A,1]
    const float* Rij   = (const float*)d_in[1];   // [P,3]
    const float* R     = (const float*)d_in[2];   // [A,3]
    const float* cell  = (const float*)d_in[3];   // [M,3,3]
    const float* kvecs = (const float*)d_in[4];   // [K,3]
    const int*   idx_m = (const int*)d_in[5];     // [A]
    const int*   idx_i = (const int*)d_in[6];     // [P]
    const int*   idx_j = (const int*)d_in[7];     // [P]

    int natoms = in_sizes[0];
    int npairs = in_sizes[1] / 3;
    int nmol   = in_sizes[3] / 9;
    int nk     = in_sizes[4] / 3;
    float* out = (float*)d_out;

    // workspace layout (float offsets; S4 16B-aligned, QM 8B-aligned)
    float* W      = (float*)d_ws;
    float* RB     = W;                                       // 576
    float* VB     = RB + 576;                                // 64
    int*   bounds = (int*)(VB + 64);                         // 80 ints (padded)
    float4* S4    = (float4*)(W + 720);                      // natoms float4
    float2* QM    = (float2*)(W + 720 + 4 * (size_t)natoms); // natoms float2
    float* QR     = W + 720 + 6 * (size_t)natoms;            // nmol*nk
    float* QI     = QR + (size_t)nmol * nk;                  // nmol*nk
    float* SI     = QI + (size_t)nmol * nk;                  // 64
    float* YRpad  = SI + 64;                                 // 64*16

    size_t zero_bytes = ((size_t)2 * nmol * nk + 64 + 64 * 16) * sizeof(float);
    (void)hipMemsetAsync(QR, 0, zero_bytes, stream);

    int nrb = (npairs + 2047) / 2048;                        // 8 pairs/thread, 256 thr
    k_cell  <<<1, 64, 0, stream>>>(cell, RB, VB, nmol);
    k_bounds<<<1, 128, 0, stream>>>(idx_m, bounds, natoms, nmol);
    k_atoms <<<(natoms + 255) / 256, 256, 0, stream>>>(R, q, idx_m, RB, S4, QM, SI, natoms);
    k_main  <<<NRECIP + nrb, 256, 0, stream>>>(S4, kvecs, bounds, QR, QI, nk,
                                               Rij, idx_i, idx_j, QM, YRpad, npairs);
    k_final <<<nmol, 256, 0, stream>>>(kvecs, RB, VB, QR, QI, YRpad, SI, out, nk);
}

// Round 5
// 261.637 us; speedup vs baseline: 1.2392x; 1.0118x over previous
//
#include <hip/hip_runtime.h>
#include <math.h>

#define KE_C     14.3996f
#define ALPHA_C  0.3f
#define CUTOFF_C 10.0f
#define TWO_PI_C 6.283185307179586f
#define INV_2PI  0.15915494309189535f
#define ASPL     32
#define NK2      512           // padded half-k slot count (510 real)

typedef float vfloat4 __attribute__((ext_vector_type(4)));
typedef int   vint4   __attribute__((ext_vector_type(4)));

// fast erfc: Abramowitz & Stegun 7.1.26, |abs err| < 1.5e-7
__device__ __forceinline__ float fast_erfc(float x) {
    float t = __builtin_amdgcn_rcpf(fmaf(0.3275911f, x, 1.0f));
    float p = fmaf(t, 1.061405429f, -1.453152027f);
    p = fmaf(t, p, 1.421413741f);
    p = fmaf(t, p, -0.284496736f);
    p = fmaf(t, p, 0.254829592f);
    return t * p * __expf(-x * x);
}

// sin/cos of 2*pi*x via raw HW ops (input in revolutions)
__device__ __forceinline__ void sincos_rev(float x, float* s, float* c) {
    float f = __builtin_amdgcn_fractf(x);
    *s = __builtin_amdgcn_sinf(f);
    *c = __builtin_amdgcn_cosf(f);
}

// ---------------- kernel 1: per-molecule reciprocal box + |det| ----------------
__global__ __launch_bounds__(64) void k_cell(const float* __restrict__ cell,
                                             float* __restrict__ RB,
                                             float* __restrict__ VB, int nmol) {
    int m = blockIdx.x * blockDim.x + threadIdx.x;
    if (m >= nmol) return;
    const float* c = cell + m * 9;
    float a00 = c[0], a01 = c[1], a02 = c[2];
    float a10 = c[3], a11 = c[4], a12 = c[5];
    float a20 = c[6], a21 = c[7], a22 = c[8];
    float det = a00 * (a11 * a22 - a12 * a21)
              - a01 * (a10 * a22 - a12 * a20)
              + a02 * (a10 * a21 - a11 * a20);
    float id = 1.0f / det;
    float inv00 = (a11 * a22 - a12 * a21) * id;
    float inv01 = (a02 * a21 - a01 * a22) * id;
    float inv02 = (a01 * a12 - a02 * a11) * id;
    float inv10 = (a12 * a20 - a10 * a22) * id;
    float inv11 = (a00 * a22 - a02 * a20) * id;
    float inv12 = (a02 * a10 - a00 * a12) * id;
    float inv20 = (a10 * a21 - a11 * a20) * id;
    float inv21 = (a01 * a20 - a00 * a21) * id;
    float inv22 = (a00 * a11 - a01 * a10) * id;
    float* rb = RB + m * 9;   // recip_box[d][e] = 2*pi * inv[e][d]
    rb[0] = TWO_PI_C * inv00; rb[1] = TWO_PI_C * inv10; rb[2] = TWO_PI_C * inv20;
    rb[3] = TWO_PI_C * inv01; rb[4] = TWO_PI_C * inv11; rb[5] = TWO_PI_C * inv21;
    rb[6] = TWO_PI_C * inv02; rb[7] = TWO_PI_C * inv12; rb[8] = TWO_PI_C * inv22;
    VB[m] = fabsf(det);
}

// ---------------- kernel 1b: molecule segment bounds (idx_m is sorted) ----------------
__global__ __launch_bounds__(128) void k_bounds(const int* __restrict__ idx_m,
                                                int* __restrict__ bounds,
                                                int natoms, int nmol) {
    int m = threadIdx.x;
    if (m > nmol) return;
    int lo = 0, hi = natoms;
    while (lo < hi) {
        int mid = (lo + hi) >> 1;
        if (idx_m[mid] < m) lo = mid + 1; else hi = mid;
    }
    bounds[m] = lo;
}

// ---------------- kernel 1c: compact half-space k list (g and -g are both present;
// q_dens(g)==q_dens(-g), so keep lexicographically-positive g, weight 2 in k_final) --------
__global__ __launch_bounds__(256) void k_khalf(const float* __restrict__ kvecs,
                                               float4* __restrict__ KH,
                                               int* __restrict__ cnt, int nk) {
    int k = blockIdx.x * 256 + threadIdx.x;
    if (k >= nk) return;
    float gx = kvecs[3 * k], gy = kvecs[3 * k + 1], gz = kvecs[3 * k + 2];
    bool pos = (gx > 0.5f) ||
               (fabsf(gx) < 0.5f && (gy > 0.5f ||
                (fabsf(gy) < 0.5f && gz > 0.5f)));
    if (pos) {
        int s = atomicAdd(cnt, 1);
        KH[s] = make_float4(gx, gy, gz, 0.0f);
    }
}

// ---------------- kernel 2: per-atom s_rev = inv(cell)^T.R (revolutions); q; self-int ------
__global__ __launch_bounds__(256) void k_atoms(const float* __restrict__ R,
                                               const float* __restrict__ q,
                                               const int* __restrict__ idx_m,
                                               const float* __restrict__ RB,
                                               float4* __restrict__ S4,
                                               float2* __restrict__ QM,
                                               float* __restrict__ SI, int natoms) {
    __shared__ float si[64];
    int tid = threadIdx.x;
    if (tid < 64) si[tid] = 0.0f;
    __syncthreads();
    int a = blockIdx.x * 256 + tid;
    if (a < natoms) {
        int m = idx_m[a];
        float r0 = R[3 * a], r1 = R[3 * a + 1], r2 = R[3 * a + 2];
        const float* rb = RB + m * 9;
        float s0 = (rb[0] * r0 + rb[1] * r1 + rb[2] * r2) * INV_2PI;
        float s1 = (rb[3] * r0 + rb[4] * r1 + rb[5] * r2) * INV_2PI;
        float s2 = (rb[6] * r0 + rb[7] * r1 + rb[8] * r2) * INV_2PI;
        float qa = q[a];
        S4[a] = make_float4(s0, s1, s2, qa);
        QM[a] = make_float2(qa, __int_as_float(m));
        atomicAdd(&si[m & 63], qa * qa);
    }
    __syncthreads();
    if (tid < 64) atomicAdd(&SI[tid], si[tid]);
}

// ---------------- fused main kernel: recip blocks [0,nrecip), real blocks after ----------------
__global__ __launch_bounds__(256) void k_main(const float4* __restrict__ S4,
                                              const float4* __restrict__ KH,
                                              const int* __restrict__ bounds,
                                              float* __restrict__ QR,
                                              float* __restrict__ QI, int nrecip,
                                              const float* __restrict__ Rij,
                                              const int* __restrict__ idx_i,
                                              const int* __restrict__ idx_j,
                                              const float2* __restrict__ QM,
                                              float* __restrict__ YRpad, int npairs) {
    __shared__ float acc[4][64];
    int tid = threadIdx.x;
    int bid = blockIdx.x;

    if (bid < nrecip) {
        // ---- reciprocal: 2 half-k slots per thread, wave-uniform atom loads ----
        int m  = bid / ASPL;
        int ac = bid % ASPL;
        int s0 = bounds[m], s1 = bounds[m + 1];
        int per = (s1 - s0 + ASPL - 1) / ASPL;
        int a0 = s0 + ac * per;
        int a1 = min(a0 + per, s1);
        float4 g0 = KH[tid];            // pad slots are zero -> harmless
        float4 g1 = KH[tid + 256];
        float qr0 = 0.f, qi0 = 0.f, qr1 = 0.f, qi1 = 0.f;
#pragma unroll 4
        for (int t = a0; t < a1; ++t) {
            float4 s = S4[t];           // uniform address -> scalar load
            float ph0 = fmaf(g0.x, s.x, fmaf(g0.y, s.y, g0.z * s.z));
            float ph1 = fmaf(g1.x, s.x, fmaf(g1.y, s.y, g1.z * s.z));
            float sn0, cs0, sn1, cs1;
            sincos_rev(ph0, &sn0, &cs0);
            sincos_rev(ph1, &sn1, &cs1);
            qr0 = fmaf(s.w, cs0, qr0);
            qi0 = fmaf(s.w, sn0, qi0);
            qr1 = fmaf(s.w, cs1, qr1);
            qi1 = fmaf(s.w, sn1, qi1);
        }
        atomicAdd(&QR[m * NK2 + tid], qr0);
        atomicAdd(&QI[m * NK2 + tid], qi0);
        atomicAdd(&QR[m * NK2 + tid + 256], qr1);
        atomicAdd(&QI[m * NK2 + tid + 256], qi1);
    } else {
        // ---- real space: 8 pairs per thread, one chunk per thread ----
        int wave = tid >> 6;
        ((float*)acc)[tid] = 0.0f;
        __syncthreads();
        const float sqa = 0.5477225575051661f;      // sqrt(0.3)
        const float frcut = fast_erfc(sqa * CUTOFF_C) / CUTOFF_C;
        long base = ((long)(bid - nrecip) * 256 + tid) << 3;
        if (base + 8 <= npairs) {
            vint4 ii0 = __builtin_nontemporal_load((const vint4*)(idx_i + base));
            vint4 ii1 = __builtin_nontemporal_load((const vint4*)(idx_i + base) + 1);
            vint4 jj0 = __builtin_nontemporal_load((const vint4*)(idx_j + base));
            vint4 jj1 = __builtin_nontemporal_load((const vint4*)(idx_j + base) + 1);
            const vfloat4* r4 = (const vfloat4*)(Rij + 3 * base);
            vfloat4 A = __builtin_nontemporal_load(r4 + 0);
            vfloat4 B = __builtin_nontemporal_load(r4 + 1);
            vfloat4 C = __builtin_nontemporal_load(r4 + 2);
            vfloat4 D = __builtin_nontemporal_load(r4 + 3);
            vfloat4 E = __builtin_nontemporal_load(r4 + 4);
            vfloat4 F = __builtin_nontemporal_load(r4 + 5);
            float2 qa0 = QM[ii0.x], qa1 = QM[ii0.y], qa2 = QM[ii0.z], qa3 = QM[ii0.w];
            float2 qa4 = QM[ii1.x], qa5 = QM[ii1.y], qa6 = QM[ii1.z], qa7 = QM[ii1.w];
            float2 qb0 = QM[jj0.x], qb1 = QM[jj0.y], qb2 = QM[jj0.z], qb3 = QM[jj0.w];
            float2 qb4 = QM[jj1.x], qb5 = QM[jj1.y], qb6 = QM[jj1.z], qb7 = QM[jj1.w];
#define PAIR(xx, yy, zz, qa, qb)                                              \
            {                                                                 \
                float d2 = fmaf(xx, xx, fmaf(yy, yy, (zz) * (zz)));           \
                if (d2 <= CUTOFF_C * CUTOFF_C) {                              \
                    float rd = __builtin_amdgcn_rsqf(d2);                     \
                    float d = d2 * rd;                                        \
                    float f = fast_erfc(sqa * d) * rd - frcut;                \
                    atomicAdd(&acc[wave][__float_as_int((qa).y) & 63],        \
                              (qa).x * (qb).x * f);                           \
                }                                                             \
            }
            PAIR(A.x, A.y, A.z, qa0, qb0)
            PAIR(A.w, B.x, B.y, qa1, qb1)
            PAIR(B.z, B.w, C.x, qa2, qb2)
            PAIR(C.y, C.z, C.w, qa3, qb3)
            PAIR(D.x, D.y, D.z, qa4, qb4)
            PAIR(D.w, E.x, E.y, qa5, qb5)
            PAIR(E.z, E.w, F.x, qa6, qb6)
            PAIR(F.y, F.z, F.w, qa7, qb7)
#undef PAIR
        } else if (base < npairs) {
            for (long p = base; p < npairs; ++p) {
                float x = Rij[3 * p], y = Rij[3 * p + 1], z = Rij[3 * p + 2];
                float d2 = fmaf(x, x, fmaf(y, y, z * z));
                if (d2 <= CUTOFF_C * CUTOFF_C) {
                    float rd = __builtin_amdgcn_rsqf(d2);
                    float d = d2 * rd;
                    float2 qi2 = QM[idx_i[p]];
                    float2 qj2 = QM[idx_j[p]];
                    atomicAdd(&acc[wave][__float_as_int(qi2.y) & 63],
                              qi2.x * qj2.x * (fast_erfc(sqa * d) * rd - frcut));
                }
            }
        }
        __syncthreads();
        if (tid < 64) {
            float v = acc[0][tid] + acc[1][tid] + acc[2][tid] + acc[3][tid];
            atomicAdd(&YRpad[tid * 16], v);
        }
    }
}

// ---------------- finalize per molecule (half-space k, weight 2) ----------------
__global__ __launch_bounds__(256) void k_final(const float4* __restrict__ KH,
                                               const int* __restrict__ cnt,
                                               const float* __restrict__ RB,
                                               const float* __restrict__ VB,
                                               const float* __restrict__ QR,
                                               const float* __restrict__ QI,
                                               const float* __restrict__ YRpad,
                                               const float* __restrict__ SI,
                                               float* __restrict__ out) {
    int m = blockIdx.x;
    int tid = threadIdx.x;
    __shared__ float rb[9];
    __shared__ float wsum[4];
    if (tid < 9) rb[tid] = RB[m * 9 + tid];
    __syncthreads();
    int nhalf = cnt[0];
    float acc = 0.0f;
    for (int k = tid; k < nhalf; k += 256) {
        float4 g = KH[k];
        float kv0 = g.x * rb[0] + g.y * rb[3] + g.z * rb[6];
        float kv1 = g.x * rb[1] + g.y * rb[4] + g.z * rb[7];
        float kv2 = g.x * rb[2] + g.y * rb[5] + g.z * rb[8];
        float ksq = kv0 * kv0 + kv1 * kv1 + kv2 * kv2;
        float qr = QR[m * NK2 + k], qi = QI[m * NK2 + k];
        acc += (qr * qr + qi * qi) * __expf(-0.25f / ALPHA_C * ksq) / ksq;
    }
#pragma unroll
    for (int off = 32; off > 0; off >>= 1) acc += __shfl_down(acc, off, 64);
    if ((tid & 63) == 0) wsum[tid >> 6] = acc;
    __syncthreads();
    if (tid == 0) {
        float s = 2.0f * (wsum[0] + wsum[1] + wsum[2] + wsum[3]);   // +g / -g symmetry
        float pref = TWO_PI_C / VB[m];
        float self_c = sqrtf(ALPHA_C / 3.14159265358979323846f);
        out[m] = 0.5f * KE_C * YRpad[m * 16] + KE_C * (pref * s - self_c * SI[m]);
    }
}

extern "C" void kernel_launch(void* const* d_in, const int* in_sizes, int n_in,
                              void* d_out, int out_size, void* d_ws, size_t ws_size,
                              hipStream_t stream) {
    const float* q     = (const float*)d_in[0];   // [A,1]
    const float* Rij   = (const float*)d_in[1];   // [P,3]
    const float* R     = (const float*)d_in[2];   // [A,3]
    const float* cell  = (const float*)d_in[3];   // [M,3,3]
    const float* kvecs = (const float*)d_in[4];   // [K,3]
    const int*   idx_m = (const int*)d_in[5];     // [A]
    const int*   idx_i = (const int*)d_in[6];     // [P]
    const int*   idx_j = (const int*)d_in[7];     // [P]

    int natoms = in_sizes[0];
    int npairs = in_sizes[1] / 3;
    int nmol   = in_sizes[3] / 9;
    int nk     = in_sizes[4] / 3;
    float* out = (float*)d_out;

    // workspace layout (float offsets; S4/KH 16B-aligned)
    float*  W      = (float*)d_ws;
    float*  RB     = W;                                        // 576
    float*  VB     = RB + 576;                                 // 64
    int*    bounds = (int*)(VB + 64);                          // 80 ints (padded)
    float4* S4     = (float4*)(W + 720);                       // natoms float4
    float2* QM     = (float2*)(W + 720 + 4 * (size_t)natoms);  // natoms float2
    // ---- zeroed region starts here (16B aligned: 720+6*natoms even*... ) ----
    size_t  zoff   = 720 + 6 * (size_t)natoms;
    zoff = (zoff + 3) & ~(size_t)3;                            // 16B align
    float4* KH     = (float4*)(W + zoff);                      // NK2 float4 = 2048 floats
    float*  QR     = W + zoff + 4 * NK2;                       // nmol*NK2
    float*  QI     = QR + (size_t)nmol * NK2;                  // nmol*NK2
    float*  SI     = QI + (size_t)nmol * NK2;                  // 64
    float*  YRpad  = SI + 64;                                  // 64*16
    int*    cnt    = (int*)(YRpad + 64 * 16);                  // 4
    size_t zero_bytes = (4 * NK2 + (size_t)2 * nmol * NK2 + 64 + 64 * 16 + 4) * sizeof(float);
    (void)hipMemsetAsync(KH, 0, zero_bytes, stream);

    int nrecip = nmol * ASPL;                                  // 2048
    int nrb = (npairs + 2047) / 2048;                          // 8 pairs/thread, 256 thr
    k_cell  <<<1, 64, 0, stream>>>(cell, RB, VB, nmol);
    k_bounds<<<1, 128, 0, stream>>>(idx_m, bounds, natoms, nmol);
    k_khalf <<<(nk + 255) / 256, 256, 0, stream>>>(kvecs, KH, cnt, nk);
    k_atoms <<<(natoms + 255) / 256, 256, 0, stream>>>(R, q, idx_m, RB, S4, QM, SI, natoms);
    k_main  <<<nrecip + nrb, 256, 0, stream>>>(S4, KH, bounds, QR, QI, nrecip,
                                               Rij, idx_i, idx_j, QM, YRpad, npairs);
    k_final <<<nmol, 256, 0, stream>>>(KH, cnt, RB, VB, QR, QI, YRpad, SI, out);
}

// Round 6
// 247.118 us; speedup vs baseline: 1.3120x; 1.0588x over previous
//
#include <hip/hip_runtime.h>
#include <math.h>

#define KE_C     14.3996f
#define ALPHA_C  0.3f
#define CUTOFF_C 10.0f
#define TWO_PI_C 6.283185307179586f
#define INV_2PI  0.15915494309189535f
#define ASPL     32
#define NK2      512           // padded half-k slot count (510 real)
#define NREAL    2048          // real-space blocks (32 waves/CU exactly)

typedef float vfloat4 __attribute__((ext_vector_type(4)));
typedef int   vint4   __attribute__((ext_vector_type(4)));

// fast erfc: Abramowitz & Stegun 7.1.26, |abs err| < 1.5e-7
__device__ __forceinline__ float fast_erfc(float x) {
    float t = __builtin_amdgcn_rcpf(fmaf(0.3275911f, x, 1.0f));
    float p = fmaf(t, 1.061405429f, -1.453152027f);
    p = fmaf(t, p, 1.421413741f);
    p = fmaf(t, p, -0.284496736f);
    p = fmaf(t, p, 0.254829592f);
    return t * p * __expf(-x * x);
}

// sin/cos of 2*pi*x via raw HW ops (input in revolutions)
__device__ __forceinline__ void sincos_rev(float x, float* s, float* c) {
    float f = __builtin_amdgcn_fractf(x);
    *s = __builtin_amdgcn_sinf(f);
    *c = __builtin_amdgcn_cosf(f);
}

// ---------------- kernel 1: per-molecule reciprocal box + |det| ----------------
__global__ __launch_bounds__(64) void k_cell(const float* __restrict__ cell,
                                             float* __restrict__ RB,
                                             float* __restrict__ VB, int nmol) {
    int m = blockIdx.x * blockDim.x + threadIdx.x;
    if (m >= nmol) return;
    const float* c = cell + m * 9;
    float a00 = c[0], a01 = c[1], a02 = c[2];
    float a10 = c[3], a11 = c[4], a12 = c[5];
    float a20 = c[6], a21 = c[7], a22 = c[8];
    float det = a00 * (a11 * a22 - a12 * a21)
              - a01 * (a10 * a22 - a12 * a20)
              + a02 * (a10 * a21 - a11 * a20);
    float id = 1.0f / det;
    float inv00 = (a11 * a22 - a12 * a21) * id;
    float inv01 = (a02 * a21 - a01 * a22) * id;
    float inv02 = (a01 * a12 - a02 * a11) * id;
    float inv10 = (a12 * a20 - a10 * a22) * id;
    float inv11 = (a00 * a22 - a02 * a20) * id;
    float inv12 = (a02 * a10 - a00 * a12) * id;
    float inv20 = (a10 * a21 - a11 * a20) * id;
    float inv21 = (a01 * a20 - a00 * a21) * id;
    float inv22 = (a00 * a11 - a01 * a10) * id;
    float* rb = RB + m * 9;   // recip_box[d][e] = 2*pi * inv[e][d]
    rb[0] = TWO_PI_C * inv00; rb[1] = TWO_PI_C * inv10; rb[2] = TWO_PI_C * inv20;
    rb[3] = TWO_PI_C * inv01; rb[4] = TWO_PI_C * inv11; rb[5] = TWO_PI_C * inv21;
    rb[6] = TWO_PI_C * inv02; rb[7] = TWO_PI_C * inv12; rb[8] = TWO_PI_C * inv22;
    VB[m] = fabsf(det);
}

// ---------------- kernel 1b: molecule segment bounds (idx_m is sorted) ----------------
__global__ __launch_bounds__(128) void k_bounds(const int* __restrict__ idx_m,
                                                int* __restrict__ bounds,
                                                int natoms, int nmol) {
    int m = threadIdx.x;
    if (m > nmol) return;
    int lo = 0, hi = natoms;
    while (lo < hi) {
        int mid = (lo + hi) >> 1;
        if (idx_m[mid] < m) lo = mid + 1; else hi = mid;
    }
    bounds[m] = lo;
}

// ---------------- kernel 1c: compact half-space k list ----------------
__global__ __launch_bounds__(256) void k_khalf(const float* __restrict__ kvecs,
                                               float4* __restrict__ KH,
                                               int* __restrict__ cnt, int nk) {
    int k = blockIdx.x * 256 + threadIdx.x;
    if (k >= nk) return;
    float gx = kvecs[3 * k], gy = kvecs[3 * k + 1], gz = kvecs[3 * k + 2];
    bool pos = (gx > 0.5f) ||
               (fabsf(gx) < 0.5f && (gy > 0.5f ||
                (fabsf(gy) < 0.5f && gz > 0.5f)));
    if (pos) {
        int s = atomicAdd(cnt, 1);
        KH[s] = make_float4(gx, gy, gz, 0.0f);
    }
}

// ---------------- kernel 2: per-atom phase (revolutions); packed (q|mol); self-int -------
__global__ __launch_bounds__(256) void k_atoms(const float* __restrict__ R,
                                               const float* __restrict__ q,
                                               const int* __restrict__ idx_m,
                                               const float* __restrict__ RB,
                                               float4* __restrict__ S4,
                                               unsigned int* __restrict__ QP,
                                               float* __restrict__ SI, int natoms) {
    __shared__ float si[64];
    int tid = threadIdx.x;
    if (tid < 64) si[tid] = 0.0f;
    __syncthreads();
    int a = blockIdx.x * 256 + tid;
    if (a < natoms) {
        int m = idx_m[a];
        float r0 = R[3 * a], r1 = R[3 * a + 1], r2 = R[3 * a + 2];
        const float* rb = RB + m * 9;
        float s0 = (rb[0] * r0 + rb[1] * r1 + rb[2] * r2) * INV_2PI;
        float s1 = (rb[3] * r0 + rb[4] * r1 + rb[5] * r2) * INV_2PI;
        float s2 = (rb[6] * r0 + rb[7] * r1 + rb[8] * r2) * INV_2PI;
        float qa = q[a];
        S4[a] = make_float4(s0, s1, s2, qa);
        // pack: clear low 6 mantissa bits of q (rel err 2^-17), stuff mol id
        QP[a] = (__float_as_uint(qa) & ~63u) | (unsigned int)(m & 63);
        atomicAdd(&si[m & 63], qa * qa);
    }
    __syncthreads();
    if (tid < 64) atomicAdd(&SI[tid], si[tid]);
}

// ---------------- fused main kernel: recip blocks [0,nrecip), real blocks after -----------
__global__ __launch_bounds__(256) void k_main(const float4* __restrict__ S4,
                                              const float4* __restrict__ KH,
                                              const int* __restrict__ bounds,
                                              float* __restrict__ QR,
                                              float* __restrict__ QI, int nrecip,
                                              const float* __restrict__ Rij,
                                              const int* __restrict__ idx_i,
                                              const int* __restrict__ idx_j,
                                              const unsigned int* __restrict__ QP,
                                              float* __restrict__ YRpad, int npairs) {
    __shared__ float acc[4][64];
    int tid = threadIdx.x;
    int bid = blockIdx.x;

    if (bid < nrecip) {
        // ---- reciprocal: 2 half-k slots per thread, wave-uniform atom loads ----
        int m  = bid / ASPL;
        int ac = bid % ASPL;
        int s0 = bounds[m], s1 = bounds[m + 1];
        int per = (s1 - s0 + ASPL - 1) / ASPL;
        int a0 = s0 + ac * per;
        int a1 = min(a0 + per, s1);
        float4 g0 = KH[tid];            // pad slots are zero -> harmless
        float4 g1 = KH[tid + 256];
        float qr0 = 0.f, qi0 = 0.f, qr1 = 0.f, qi1 = 0.f;
#pragma unroll 4
        for (int t = a0; t < a1; ++t) {
            float4 s = S4[t];           // uniform address -> scalar load
            float ph0 = fmaf(g0.x, s.x, fmaf(g0.y, s.y, g0.z * s.z));
            float ph1 = fmaf(g1.x, s.x, fmaf(g1.y, s.y, g1.z * s.z));
            float sn0, cs0, sn1, cs1;
            sincos_rev(ph0, &sn0, &cs0);
            sincos_rev(ph1, &sn1, &cs1);
            qr0 = fmaf(s.w, cs0, qr0);
            qi0 = fmaf(s.w, sn0, qi0);
            qr1 = fmaf(s.w, cs1, qr1);
            qi1 = fmaf(s.w, sn1, qi1);
        }
        atomicAdd(&QR[m * NK2 + tid], qr0);
        atomicAdd(&QI[m * NK2 + tid], qi0);
        atomicAdd(&QR[m * NK2 + tid + 256], qr1);
        atomicAdd(&QI[m * NK2 + tid + 256], qi1);
    } else {
        // ---- real space: 4-pair chunks, grid-stride, branchless cutoff ----
        int wave = tid >> 6;
        ((float*)acc)[tid] = 0.0f;
        __syncthreads();
        const float sqa = 0.5477225575051661f;      // sqrt(0.3)
        const float frcut = fast_erfc(sqa * CUTOFF_C) / CUTOFF_C;
        int nchunk = npairs >> 2;
        int stride = NREAL * 256;
        for (int c = (bid - nrecip) * 256 + tid; c < nchunk; c += stride) {
            int p = c << 2;
            vint4 ii = *(const vint4*)(idx_i + p);
            vint4 jj = *(const vint4*)(idx_j + p);
            const vfloat4* r4 = (const vfloat4*)(Rij + 3 * p);
            vfloat4 A = r4[0], B = r4[1], C = r4[2];
            unsigned int ui0 = QP[ii.x], ui1 = QP[ii.y], ui2 = QP[ii.z], ui3 = QP[ii.w];
            unsigned int uj0 = QP[jj.x], uj1 = QP[jj.y], uj2 = QP[jj.z], uj3 = QP[jj.w];
#define PAIR(xx, yy, zz, ui, uj)                                              \
            {                                                                 \
                float d2 = fmaf(xx, xx, fmaf(yy, yy, (zz) * (zz)));           \
                float rd = __builtin_amdgcn_rsqf(d2);                         \
                float d = d2 * rd;                                            \
                float f = fast_erfc(sqa * d) * rd - frcut;                    \
                f = (d2 <= CUTOFF_C * CUTOFF_C) ? f : 0.0f;                   \
                float qi_ = __uint_as_float((ui) & ~63u);                     \
                float qj_ = __uint_as_float((uj) & ~63u);                     \
                atomicAdd(&acc[wave][(ui) & 63u], qi_ * qj_ * f);             \
            }
            PAIR(A.x, A.y, A.z, ui0, uj0)
            PAIR(A.w, B.x, B.y, ui1, uj1)
            PAIR(B.z, B.w, C.x, ui2, uj2)
            PAIR(C.y, C.z, C.w, ui3, uj3)
#undef PAIR
        }
        // tail (npairs not multiple of 4)
        if (bid == nrecip && tid == 0) {
            for (int p = (npairs >> 2) << 2; p < npairs; ++p) {
                float x = Rij[3 * p], y = Rij[3 * p + 1], z = Rij[3 * p + 2];
                float d2 = fmaf(x, x, fmaf(y, y, z * z));
                if (d2 <= CUTOFF_C * CUTOFF_C) {
                    float rd = __builtin_amdgcn_rsqf(d2);
                    float d = d2 * rd;
                    unsigned int ui = QP[idx_i[p]], uj = QP[idx_j[p]];
                    float qi_ = __uint_as_float(ui & ~63u);
                    float qj_ = __uint_as_float(uj & ~63u);
                    atomicAdd(&acc[0][ui & 63u],
                              qi_ * qj_ * (fast_erfc(sqa * d) * rd - frcut));
                }
            }
        }
        __syncthreads();
        if (tid < 64) {
            float v = acc[0][tid] + acc[1][tid] + acc[2][tid] + acc[3][tid];
            atomicAdd(&YRpad[tid * 16], v);
        }
    }
}

// ---------------- finalize per molecule (half-space k, weight 2) ----------------
__global__ __launch_bounds__(256) void k_final(const float4* __restrict__ KH,
                                               const int* __restrict__ cnt,
                                               const float* __restrict__ RB,
                                               const float* __restrict__ VB,
                                               const float* __restrict__ QR,
                                               const float* __restrict__ QI,
                                               const float* __restrict__ YRpad,
                                               const float* __restrict__ SI,
                                               float* __restrict__ out) {
    int m = blockIdx.x;
    int tid = threadIdx.x;
    __shared__ float rb[9];
    __shared__ float wsum[4];
    if (tid < 9) rb[tid] = RB[m * 9 + tid];
    __syncthreads();
    int nhalf = cnt[0];
    float acc = 0.0f;
    for (int k = tid; k < nhalf; k += 256) {
        float4 g = KH[k];
        float kv0 = g.x * rb[0] + g.y * rb[3] + g.z * rb[6];
        float kv1 = g.x * rb[1] + g.y * rb[4] + g.z * rb[7];
        float kv2 = g.x * rb[2] + g.y * rb[5] + g.z * rb[8];
        float ksq = kv0 * kv0 + kv1 * kv1 + kv2 * kv2;
        float qr = QR[m * NK2 + k], qi = QI[m * NK2 + k];
        acc += (qr * qr + qi * qi) * __expf(-0.25f / ALPHA_C * ksq) / ksq;
    }
#pragma unroll
    for (int off = 32; off > 0; off >>= 1) acc += __shfl_down(acc, off, 64);
    if ((tid & 63) == 0) wsum[tid >> 6] = acc;
    __syncthreads();
    if (tid == 0) {
        float s = 2.0f * (wsum[0] + wsum[1] + wsum[2] + wsum[3]);   // +g / -g symmetry
        float pref = TWO_PI_C / VB[m];
        float self_c = sqrtf(ALPHA_C / 3.14159265358979323846f);
        out[m] = 0.5f * KE_C * YRpad[m * 16] + KE_C * (pref * s - self_c * SI[m]);
    }
}

extern "C" void kernel_launch(void* const* d_in, const int* in_sizes, int n_in,
                              void* d_out, int out_size, void* d_ws, size_t ws_size,
                              hipStream_t stream) {
    const float* q     = (const float*)d_in[0];   // [A,1]
    const float* Rij   = (const float*)d_in[1];   // [P,3]
    const float* R     = (const float*)d_in[2];   // [A,3]
    const float* cell  = (const float*)d_in[3];   // [M,3,3]
    const float* kvecs = (const float*)d_in[4];   // [K,3]
    const int*   idx_m = (const int*)d_in[5];     // [A]
    const int*   idx_i = (const int*)d_in[6];     // [P]
    const int*   idx_j = (const int*)d_in[7];     // [P]

    int natoms = in_sizes[0];
    int npairs = in_sizes[1] / 3;
    int nmol   = in_sizes[3] / 9;
    int nk     = in_sizes[4] / 3;
    float* out = (float*)d_out;

    // workspace layout (float offsets; S4/KH 16B-aligned)
    float*  W      = (float*)d_ws;
    float*  RB     = W;                                        // 576
    float*  VB     = RB + 576;                                 // 64
    int*    bounds = (int*)(VB + 64);                          // 80 ints (padded)
    float4* S4     = (float4*)(W + 720);                       // natoms float4
    unsigned int* QP = (unsigned int*)(W + 720 + 4 * (size_t)natoms); // natoms u32
    size_t  zoff   = 720 + 5 * (size_t)natoms;
    zoff = (zoff + 3) & ~(size_t)3;                            // 16B align
    float4* KH     = (float4*)(W + zoff);                      // NK2 float4
    float*  QR     = W + zoff + 4 * NK2;                       // nmol*NK2
    float*  QI     = QR + (size_t)nmol * NK2;                  // nmol*NK2
    float*  SI     = QI + (size_t)nmol * NK2;                  // 64
    float*  YRpad  = SI + 64;                                  // 64*16
    int*    cnt    = (int*)(YRpad + 64 * 16);                  // 4
    size_t zero_bytes = (4 * NK2 + (size_t)2 * nmol * NK2 + 64 + 64 * 16 + 4) * sizeof(float);
    (void)hipMemsetAsync(KH, 0, zero_bytes, stream);

    int nrecip = nmol * ASPL;                                  // 2048
    k_cell  <<<1, 64, 0, stream>>>(cell, RB, VB, nmol);
    k_bounds<<<1, 128, 0, stream>>>(idx_m, bounds, natoms, nmol);
    k_khalf <<<(nk + 255) / 256, 256, 0, stream>>>(kvecs, KH, cnt, nk);
    k_atoms <<<(natoms + 255) / 256, 256, 0, stream>>>(R, q, idx_m, RB, S4, QP, SI, natoms);
    k_main  <<<nrecip + NREAL, 256, 0, stream>>>(S4, KH, bounds, QR, QI, nrecip,
                                                 Rij, idx_i, idx_j, QP, YRpad, npairs);
    k_final <<<nmol, 256, 0, stream>>>(KH, cnt, RB, VB, QR, QI, YRpad, SI, out);
}